// Round 4
// baseline (546.046 us; speedup 1.0000x reference)
//
#include <hip/hip_runtime.h>

typedef unsigned short u16;
typedef unsigned int u32;
typedef __bf16 bf16x8 __attribute__((ext_vector_type(8)));
typedef float f32x4 __attribute__((ext_vector_type(4)));

#define DEV static __device__ __forceinline__

constexpr int D_MODEL = 2048;
constexpr int N_HEADS = 16;
constexpr int HEAD_DIM = 128;
constexpr int BB = 2;              // batch
constexpr int S = 2048;            // seq len
constexpr int NTOK = BB * S;       // 4096
constexpr int E3 = 3 * D_MODEL;    // 6144
constexpr float CLIP_QKV = 6.0f;
constexpr float LN_EPS = 1e-5f;
constexpr float NEG_BIG = -30000.0f;  // finite mask sentinel

DEV u16 f2bf(float f) {
    u32 u = __float_as_uint(f);
    u = (u + 0x7FFFu + ((u >> 16) & 1u)) >> 16;
    return (u16)u;
}
DEV float bf2f(u16 h) { return __uint_as_float(((u32)h) << 16); }

// stage 8 fp32 -> 8 bf16 into LDS
DEV void stage8_f32(const float* __restrict__ src, u16* __restrict__ dst) {
    const float4 f0 = *reinterpret_cast<const float4*>(src);
    const float4 f1 = *reinterpret_cast<const float4*>(src + 4);
    u16 h[8] = {f2bf(f0.x), f2bf(f0.y), f2bf(f0.z), f2bf(f0.w),
                f2bf(f1.x), f2bf(f1.y), f2bf(f1.z), f2bf(f1.w)};
    *reinterpret_cast<uint4*>(dst) = *reinterpret_cast<const uint4*>(h);
}

// ---------------------------------------------------------------------------
// GEMM: C[M,N] = A[M,K] * B[N,K]^T + bias  (fp32/bf16 in, fp32 or bf16 out)
// 128x128 tile, BK=32, 256 threads = 4 waves (2x2), each wave 64x64.
// ---------------------------------------------------------------------------
template<bool DO_CLIP, bool A32, bool B32, bool OUT32>
__global__ __launch_bounds__(256)
void k_gemm_bt(const void* __restrict__ Ap, const void* __restrict__ Bp,
               const float* __restrict__ bias, void* __restrict__ Cp,
               int M, int N, int K) {
    constexpr int LDT = 40;  // lds row stride in u16
    __shared__ __align__(16) u16 As[128 * LDT];
    __shared__ __align__(16) u16 Bs[128 * LDT];

    const int tid = threadIdx.x;
    const int lane = tid & 63, w = tid >> 6;
    const int quad = lane >> 4, l16 = lane & 15;
    const int wm = w >> 1, wn = w & 1;
    const int m0 = blockIdx.y * 128, n0 = blockIdx.x * 128;

    const int r0 = tid >> 2, c0 = (tid & 3) * 8;
    const int r1 = r0 + 64;

    f32x4 acc[4][4] = {};

    for (int k0 = 0; k0 < K; k0 += 32) {
        __syncthreads();
        if (A32) {
            const float* Af = (const float*)Ap;
            stage8_f32(Af + (size_t)(m0 + r0) * K + k0 + c0, &As[r0 * LDT + c0]);
            stage8_f32(Af + (size_t)(m0 + r1) * K + k0 + c0, &As[r1 * LDT + c0]);
        } else {
            const u16* Ab = (const u16*)Ap;
            *reinterpret_cast<uint4*>(&As[r0 * LDT + c0]) =
                *reinterpret_cast<const uint4*>(Ab + (size_t)(m0 + r0) * K + k0 + c0);
            *reinterpret_cast<uint4*>(&As[r1 * LDT + c0]) =
                *reinterpret_cast<const uint4*>(Ab + (size_t)(m0 + r1) * K + k0 + c0);
        }
        if (B32) {
            const float* Bf = (const float*)Bp;
            stage8_f32(Bf + (size_t)(n0 + r0) * K + k0 + c0, &Bs[r0 * LDT + c0]);
            stage8_f32(Bf + (size_t)(n0 + r1) * K + k0 + c0, &Bs[r1 * LDT + c0]);
        } else {
            const u16* Bb = (const u16*)Bp;
            *reinterpret_cast<uint4*>(&Bs[r0 * LDT + c0]) =
                *reinterpret_cast<const uint4*>(Bb + (size_t)(n0 + r0) * K + k0 + c0);
            *reinterpret_cast<uint4*>(&Bs[r1 * LDT + c0]) =
                *reinterpret_cast<const uint4*>(Bb + (size_t)(n0 + r1) * K + k0 + c0);
        }
        __syncthreads();

        bf16x8 af[4], bfv[4];
        #pragma unroll
        for (int mt = 0; mt < 4; ++mt)
            af[mt] = *reinterpret_cast<const bf16x8*>(&As[(wm * 64 + mt * 16 + l16) * LDT + quad * 8]);
        #pragma unroll
        for (int nt = 0; nt < 4; ++nt)
            bfv[nt] = *reinterpret_cast<const bf16x8*>(&Bs[(wn * 64 + nt * 16 + l16) * LDT + quad * 8]);
        #pragma unroll
        for (int mt = 0; mt < 4; ++mt)
            #pragma unroll
            for (int nt = 0; nt < 4; ++nt)
                acc[mt][nt] = __builtin_amdgcn_mfma_f32_16x16x32_bf16(af[mt], bfv[nt], acc[mt][nt], 0, 0, 0);
    }

    #pragma unroll
    for (int mt = 0; mt < 4; ++mt) {
        const int row = m0 + wm * 64 + mt * 16 + quad * 4;
        #pragma unroll
        for (int nt = 0; nt < 4; ++nt) {
            const int col = n0 + wn * 64 + nt * 16 + l16;
            const float bv = bias[col];
            #pragma unroll
            for (int r = 0; r < 4; ++r) {
                float v = acc[mt][nt][r] + bv;
                if (DO_CLIP) v = fminf(CLIP_QKV, fmaxf(-CLIP_QKV, v));
                if (OUT32)
                    ((float*)Cp)[(size_t)(row + r) * N + col] = v;
                else
                    ((u16*)Cp)[(size_t)(row + r) * N + col] = f2bf(v);
            }
        }
    }
}

// ---------------------------------------------------------------------------
// LayerNorm over d_model for q and k parts of qkv; writes head-split layouts
// qh/kh: [B, H, S, HEAD_DIM] bf16. One block (256 thr) per token.
// ---------------------------------------------------------------------------
__global__ __launch_bounds__(256)
void k_ln(const u16* __restrict__ qkvb,
          const float* __restrict__ gq, const float* __restrict__ bq,
          const float* __restrict__ gk, const float* __restrict__ bk,
          u16* __restrict__ qh, u16* __restrict__ kh) {
    __shared__ float red[8];
    const int tok = blockIdx.x;
    const int b = tok >> 11, s = tok & (S - 1);
    const int tid = threadIdx.x, lane = tid & 63, w = tid >> 6;

    #pragma unroll
    for (int part = 0; part < 2; ++part) {
        const int c0 = tid * 8;
        const u16* src = qkvb + (size_t)tok * E3 + part * D_MODEL + c0;
        u16 hx[8];
        *reinterpret_cast<uint4*>(hx) = *reinterpret_cast<const uint4*>(src);
        float x[8], sum = 0.f, sq = 0.f;
        #pragma unroll
        for (int j = 0; j < 8; ++j) { x[j] = bf2f(hx[j]); sum += x[j]; sq += x[j] * x[j]; }
        #pragma unroll
        for (int off = 1; off < 64; off <<= 1) {
            sum += __shfl_xor(sum, off, 64);
            sq  += __shfl_xor(sq,  off, 64);
        }
        __syncthreads();   // protect red[] reuse across parts
        if (lane == 0) { red[w] = sum; red[4 + w] = sq; }
        __syncthreads();
        sum = red[0] + red[1] + red[2] + red[3];
        sq  = red[4] + red[5] + red[6] + red[7];
        const float mean = sum * (1.0f / D_MODEL);
        const float var  = fmaxf(sq * (1.0f / D_MODEL) - mean * mean, 0.0f);
        const float rstd = rsqrtf(var + LN_EPS);
        const float* g  = part ? gk : gq;
        const float* be = part ? bk : bq;
        u16 o[8];
        #pragma unroll
        for (int j = 0; j < 8; ++j)
            o[j] = f2bf((x[j] - mean) * rstd * g[c0 + j] + be[c0 + j]);
        const int h = c0 >> 7, d = c0 & (HEAD_DIM - 1);
        u16* dst = (part ? kh : qh) + ((size_t)((b * N_HEADS + h) * S + s)) * HEAD_DIM + d;
        *reinterpret_cast<uint4*>(dst) = *reinterpret_cast<uint4*>(o);
    }
}

// ---------------------------------------------------------------------------
// V transpose: qkv v-part [tok, 2048] bf16 -> vt [B, H, HEAD_DIM, S] bf16.
// ---------------------------------------------------------------------------
__global__ __launch_bounds__(256)
void k_vtrans(const u16* __restrict__ qkvb, u16* __restrict__ vt) {
    constexpr int LDT = 136;  // 128 + 8 pad
    __shared__ __align__(16) u16 tile[64 * LDT];
    const int blk = blockIdx.x;
    const int st = blk & 31, h = (blk >> 5) & 15, b = blk >> 9;
    const int s0 = st * 64;
    const int tid = threadIdx.x;

    #pragma unroll
    for (int i = 0; i < 4; ++i) {
        const int chunk = tid + i * 256;
        const int row = chunk >> 4, c8 = (chunk & 15) * 8;
        const u16* src = qkvb + (size_t)(b * S + s0 + row) * E3 + 2 * D_MODEL + h * HEAD_DIM + c8;
        *reinterpret_cast<uint4*>(&tile[row * LDT + c8]) = *reinterpret_cast<const uint4*>(src);
    }
    __syncthreads();
    #pragma unroll
    for (int i = 0; i < 4; ++i) {
        const int chunk = tid + i * 256;
        const int d = chunk >> 3, s8 = (chunk & 7) * 8;
        u16 o[8];
        #pragma unroll
        for (int j = 0; j < 8; ++j) o[j] = tile[(s8 + j) * LDT + d];
        u16* dst = vt + ((size_t)(b * N_HEADS + h) * HEAD_DIM + d) * S + s0 + s8;
        *reinterpret_cast<uint4*>(dst) = *reinterpret_cast<uint4*>(o);
    }
}

// ---------------------------------------------------------------------------
// Flash attention (causal + key bias), 128 q-rows per block, 64-key kv tiles.
// ---------------------------------------------------------------------------
__global__ __launch_bounds__(256)
void k_attn(const u16* __restrict__ qh, const u16* __restrict__ kh,
            const u16* __restrict__ vt, const float* __restrict__ bias,
            u16* __restrict__ ctx) {
    constexpr int BQ = 128, BKV = 64;
    constexpr int LDK = 136;
    constexpr int LDV = 72;
    constexpr int LDP = 72;
    __shared__ __align__(16) u16 Ks[64 * LDK];
    __shared__ __align__(16) u16 Vs[128 * LDV];
    __shared__ __align__(16) u16 Ps[128 * LDP];

    const int blk = blockIdx.x;
    const int bh = blk & 31;          // b*16 + h
    const int qi = 15 - (blk >> 5);   // heavy q-tiles dispatched first
    const int b = bh >> 4, h = bh & 15;
    const int q0 = qi * BQ;

    const int tid = threadIdx.x, lane = tid & 63, w = tid >> 6;
    const int quad = lane >> 4, l16 = lane & 15;

    const size_t bhS = (size_t)(b * N_HEADS + h) * S;
    const u16* Qt = qh + (bhS + q0) * HEAD_DIM;
    const u16* Kt = kh + bhS * HEAD_DIM;
    const u16* Vt = vt + (size_t)(b * N_HEADS + h) * HEAD_DIM * S;

    bf16x8 aq[2][4];
    #pragma unroll
    for (int mt = 0; mt < 2; ++mt)
        #pragma unroll
        for (int ks = 0; ks < 4; ++ks)
            aq[mt][ks] = *reinterpret_cast<const bf16x8*>(
                Qt + (size_t)(w * 32 + mt * 16 + l16) * HEAD_DIM + ks * 32 + quad * 8);

    f32x4 o[2][8] = {};
    float m_i[2][4], l_i[2][4];
    #pragma unroll
    for (int mt = 0; mt < 2; ++mt)
        #pragma unroll
        for (int r = 0; r < 4; ++r) { m_i[mt][r] = NEG_BIG; l_i[mt][r] = 0.f; }

    const float scale = 0.08838834764831845f;  // 1/sqrt(128)
    const int nkv = 2 * (qi + 1);

    for (int t = 0; t < nkv; ++t) {
        const int k0 = t * BKV;
        __syncthreads();
        #pragma unroll
        for (int i = 0; i < 4; ++i) {   // Ks: 64 keys x 128 d
            const int chunk = tid + i * 256;
            const int key = chunk >> 4, c8 = (chunk & 15) * 8;
            *reinterpret_cast<uint4*>(&Ks[key * LDK + c8]) =
                *reinterpret_cast<const uint4*>(Kt + (size_t)(k0 + key) * HEAD_DIM + c8);
        }
        #pragma unroll
        for (int i = 0; i < 4; ++i) {   // Vs: 128 d x 64 keys (V^T)
            const int chunk = tid + i * 256;
            const int d = chunk >> 3, s8 = (chunk & 7) * 8;
            *reinterpret_cast<uint4*>(&Vs[d * LDV + s8]) =
                *reinterpret_cast<const uint4*>(Vt + (size_t)d * S + k0 + s8);
        }
        __syncthreads();

        // QK^T
        f32x4 sc[2][4] = {};
        #pragma unroll
        for (int ks = 0; ks < 4; ++ks) {
            bf16x8 bk[4];
            #pragma unroll
            for (int nt = 0; nt < 4; ++nt)
                bk[nt] = *reinterpret_cast<const bf16x8*>(&Ks[(nt * 16 + l16) * LDK + ks * 32 + quad * 8]);
            #pragma unroll
            for (int mt = 0; mt < 2; ++mt)
                #pragma unroll
                for (int nt = 0; nt < 4; ++nt)
                    sc[mt][nt] = __builtin_amdgcn_mfma_f32_16x16x32_bf16(aq[mt][ks], bk[nt], sc[mt][nt], 0, 0, 0);
        }

        // scale + bias + causal mask (finite sentinel)
        float bv[4];
        #pragma unroll
        for (int nt = 0; nt < 4; ++nt) bv[nt] = bias[h * S + k0 + nt * 16 + l16];
        const bool need_mask = (t >= 2 * qi);
        #pragma unroll
        for (int mt = 0; mt < 2; ++mt)
            #pragma unroll
            for (int nt = 0; nt < 4; ++nt) {
                const int kpos = k0 + nt * 16 + l16;
                #pragma unroll
                for (int r = 0; r < 4; ++r) {
                    float v = sc[mt][nt][r] * scale + bv[nt];
                    if (need_mask) {
                        const int qpos = q0 + w * 32 + mt * 16 + quad * 4 + r;
                        if (kpos > qpos) v = NEG_BIG;
                    }
                    sc[mt][nt][r] = v;
                }
            }

        // online softmax (rows shared by the 16 lanes of a quad)
        #pragma unroll
        for (int mt = 0; mt < 2; ++mt)
            #pragma unroll
            for (int r = 0; r < 4; ++r) {
                float mx = fmaxf(fmaxf(sc[mt][0][r], sc[mt][1][r]), fmaxf(sc[mt][2][r], sc[mt][3][r]));
                mx = fmaxf(mx, __shfl_xor(mx, 1, 64));
                mx = fmaxf(mx, __shfl_xor(mx, 2, 64));
                mx = fmaxf(mx, __shfl_xor(mx, 4, 64));
                mx = fmaxf(mx, __shfl_xor(mx, 8, 64));
                const float mnew = fmaxf(m_i[mt][r], mx);
                const float alpha = __expf(m_i[mt][r] - mnew);
                float rs = 0.f;
                #pragma unroll
                for (int nt = 0; nt < 4; ++nt) {
                    const float p = __expf(sc[mt][nt][r] - mnew);
                    sc[mt][nt][r] = p;
                    rs += p;
                }
                rs += __shfl_xor(rs, 1, 64);
                rs += __shfl_xor(rs, 2, 64);
                rs += __shfl_xor(rs, 4, 64);
                rs += __shfl_xor(rs, 8, 64);
                l_i[mt][r] = l_i[mt][r] * alpha + rs;
                m_i[mt][r] = mnew;
                #pragma unroll
                for (int nt = 0; nt < 8; ++nt) o[mt][nt][r] *= alpha;
            }

        // P -> LDS (C-layout -> A-layout round trip)
        #pragma unroll
        for (int mt = 0; mt < 2; ++mt)
            #pragma unroll
            for (int nt = 0; nt < 4; ++nt)
                #pragma unroll
                for (int r = 0; r < 4; ++r)
                    Ps[(w * 32 + mt * 16 + quad * 4 + r) * LDP + nt * 16 + l16] = f2bf(sc[mt][nt][r]);

        __syncthreads();  // uniform trip count; guarantees Ps visibility

        // PV: o += P @ V
        #pragma unroll
        for (int ks = 0; ks < 2; ++ks) {
            bf16x8 ap[2];
            #pragma unroll
            for (int mt = 0; mt < 2; ++mt)
                ap[mt] = *reinterpret_cast<const bf16x8*>(&Ps[(w * 32 + mt * 16 + l16) * LDP + ks * 32 + quad * 8]);
            #pragma unroll
            for (int nt = 0; nt < 8; ++nt) {
                const bf16x8 bvv = *reinterpret_cast<const bf16x8*>(&Vs[(nt * 16 + l16) * LDV + ks * 32 + quad * 8]);
                #pragma unroll
                for (int mt = 0; mt < 2; ++mt)
                    o[mt][nt] = __builtin_amdgcn_mfma_f32_16x16x32_bf16(ap[mt], bvv, o[mt][nt], 0, 0, 0);
            }
        }
    }

    // epilogue
    #pragma unroll
    for (int mt = 0; mt < 2; ++mt)
        #pragma unroll
        for (int r = 0; r < 4; ++r) {
            const float inv_l = 1.0f / fmaxf(l_i[mt][r], 1e-20f);
            const int row = q0 + w * 32 + mt * 16 + quad * 4 + r;
            u16* dst = ctx + (size_t)(b * S + row) * D_MODEL + h * HEAD_DIM;
            #pragma unroll
            for (int nt = 0; nt < 8; ++nt)
                dst[nt * 16 + l16] = f2bf(o[mt][nt][r] * inv_l);
        }
}

// ---------------------------------------------------------------------------
extern "C" void kernel_launch(void* const* d_in, const int* in_sizes, int n_in,
                              void* d_out, int out_size, void* d_ws, size_t ws_size,
                              hipStream_t stream) {
    const float* x        = (const float*)d_in[0];   // [B,S,D] fp32
    const float* attn_bias= (const float*)d_in[1];   // [1,H,1,S] fp32
    // d_in[2]: key_padding_mask — all True, no-op in reference
    const float* Wqkv_w   = (const float*)d_in[3];   // [3D, D] fp32
    const float* Wqkv_b   = (const float*)d_in[4];   // [3D] fp32
    const float* q_ln_g   = (const float*)d_in[5];
    const float* q_ln_b   = (const float*)d_in[6];
    const float* k_ln_g   = (const float*)d_in[7];
    const float* k_ln_b   = (const float*)d_in[8];
    const float* out_w    = (const float*)d_in[9];   // [D, D] fp32
    const float* out_b    = (const float*)d_in[10];

    char* ws = (char*)d_ws;
    u16* qkvb = (u16*)ws; ws += (size_t)NTOK * E3 * 2;        // 50.3 MB (bf16)
    u16* qhb  = (u16*)ws; ws += (size_t)NTOK * D_MODEL * 2;   // 16.8 MB
    u16* khb  = (u16*)ws; ws += (size_t)NTOK * D_MODEL * 2;
    u16* vtb  = (u16*)ws; ws += (size_t)NTOK * D_MODEL * 2;
    u16* ctxb = qkvb;   // alias: qkv dead after ln+vtrans

    k_gemm_bt<true, true, true, false><<<dim3(E3 / 128, NTOK / 128), 256, 0, stream>>>(
        x, Wqkv_w, Wqkv_b, qkvb, NTOK, E3, D_MODEL);
    k_ln<<<NTOK, 256, 0, stream>>>(qkvb, q_ln_g, q_ln_b, k_ln_g, k_ln_b, qhb, khb);
    k_vtrans<<<BB * N_HEADS * (S / 64), 256, 0, stream>>>(qkvb, vtb);
    k_attn<<<BB * N_HEADS * (S / 128), 256, 0, stream>>>(qhb, khb, vtb, attn_bias, ctxb);
    // final projection: fp32 output
    k_gemm_bt<false, false, true, true><<<dim3(D_MODEL / 128, NTOK / 128), 256, 0, stream>>>(
        ctxb, out_w, out_b, d_out, NTOK, D_MODEL, D_MODEL);
}

// Round 5
// 476.108 us; speedup vs baseline: 1.1469x; 1.1469x over previous
//
#include <hip/hip_runtime.h>

typedef unsigned short u16;
typedef unsigned int u32;
typedef __bf16 bf16x8 __attribute__((ext_vector_type(8)));
typedef float f32x4 __attribute__((ext_vector_type(4)));

#define DEV static __device__ __forceinline__

constexpr int D_MODEL = 2048;
constexpr int N_HEADS = 16;
constexpr int HEAD_DIM = 128;
constexpr int BB = 2;              // batch
constexpr int S = 2048;            // seq len
constexpr int NTOK = BB * S;       // 4096
constexpr int E3 = 3 * D_MODEL;    // 6144
constexpr float CLIP_QKV = 6.0f;
constexpr float LN_EPS = 1e-5f;
constexpr float NEG_BIG = -30000.0f;  // finite mask sentinel

DEV u16 f2bf(float f) {
    u32 u = __float_as_uint(f);
    u = (u + 0x7FFFu + ((u >> 16) & 1u)) >> 16;
    return (u16)u;
}
DEV float bf2f(u16 h) { return __uint_as_float(((u32)h) << 16); }

// pack 8 fp32 -> 8 bf16
DEV void stage8_f32(const float* __restrict__ src, u16* __restrict__ dst) {
    const float4 f0 = *reinterpret_cast<const float4*>(src);
    const float4 f1 = *reinterpret_cast<const float4*>(src + 4);
    u16 h[8] = {f2bf(f0.x), f2bf(f0.y), f2bf(f0.z), f2bf(f0.w),
                f2bf(f1.x), f2bf(f1.y), f2bf(f1.z), f2bf(f1.w)};
    *reinterpret_cast<uint4*>(dst) = *reinterpret_cast<const uint4*>(h);
}

// async 16B global -> LDS (wave-uniform LDS base + lane*16 semantics)
DEV void gload16(const u16* g, u16* l) {
    __builtin_amdgcn_global_load_lds(
        (const __attribute__((address_space(1))) void*)g,
        (__attribute__((address_space(3))) void*)l, 16, 0, 0);
}

// ---------------------------------------------------------------------------
// fp32 -> bf16 bulk convert, 8 elems/thread
// ---------------------------------------------------------------------------
__global__ __launch_bounds__(256)
void k_cvt(const float* __restrict__ s, u16* __restrict__ d, int n8) {
    const int i = blockIdx.x * 256 + threadIdx.x;
    if (i < n8) stage8_f32(s + (size_t)i * 8, d + (size_t)i * 8);
}

// ---------------------------------------------------------------------------
// GEMM: C[M,N] = A[M,K] * B[N,K]^T + bias  (bf16 in; fp32 or bf16 out)
// m97 structure: 128x128 tile, BK=32, 4 waves (2x2, 64x64 each),
// global_load_lds width-16 staging into unpadded [128][32] LDS tiles.
// ---------------------------------------------------------------------------
template<bool DO_CLIP, bool OUT32>
__global__ __launch_bounds__(256)
void k_gemm_bt(const u16* __restrict__ A, const u16* __restrict__ Bm,
               const float* __restrict__ bias, void* __restrict__ Cp,
               int M, int N, int K) {
    __shared__ __align__(16) u16 As[128 * 32];
    __shared__ __align__(16) u16 Bs[128 * 32];

    const int tid = threadIdx.x;
    const int lane = tid & 63, w = tid >> 6;
    const int quad = lane >> 4, l16 = lane & 15;
    const int wm = w >> 1, wn = w & 1;
    const int m0 = blockIdx.y * 128, n0 = blockIdx.x * 128;

    f32x4 acc[4][4] = {};

    for (int k0 = 0; k0 < K; k0 += 32) {
        __syncthreads();
        #pragma unroll
        for (int j = 0; j < 2; ++j) {
            const int c = w * 128 + j * 64 + lane;   // 16B chunk id, 0..511
            const int row = c >> 2, cc = c & 3;      // 4 chunks per 32-col row
            gload16(A  + (size_t)(m0 + row) * K + k0 + cc * 8, &As[c * 8]);
            gload16(Bm + (size_t)(n0 + row) * K + k0 + cc * 8, &Bs[c * 8]);
        }
        __syncthreads();

        bf16x8 af[4], bfv[4];
        #pragma unroll
        for (int mt = 0; mt < 4; ++mt)
            af[mt] = *reinterpret_cast<const bf16x8*>(&As[(wm * 64 + mt * 16 + l16) * 32 + quad * 8]);
        #pragma unroll
        for (int nt = 0; nt < 4; ++nt)
            bfv[nt] = *reinterpret_cast<const bf16x8*>(&Bs[(wn * 64 + nt * 16 + l16) * 32 + quad * 8]);
        #pragma unroll
        for (int mt = 0; mt < 4; ++mt)
            #pragma unroll
            for (int nt = 0; nt < 4; ++nt)
                acc[mt][nt] = __builtin_amdgcn_mfma_f32_16x16x32_bf16(af[mt], bfv[nt], acc[mt][nt], 0, 0, 0);
    }

    #pragma unroll
    for (int mt = 0; mt < 4; ++mt) {
        const int row = m0 + wm * 64 + mt * 16 + quad * 4;
        #pragma unroll
        for (int nt = 0; nt < 4; ++nt) {
            const int col = n0 + wn * 64 + nt * 16 + l16;
            const float bv = bias[col];
            #pragma unroll
            for (int r = 0; r < 4; ++r) {
                float v = acc[mt][nt][r] + bv;
                if (DO_CLIP) v = fminf(CLIP_QKV, fmaxf(-CLIP_QKV, v));
                if (OUT32)
                    ((float*)Cp)[(size_t)(row + r) * N + col] = v;
                else
                    ((u16*)Cp)[(size_t)(row + r) * N + col] = f2bf(v);
            }
        }
    }
}

// ---------------------------------------------------------------------------
// LayerNorm over d_model for q and k parts of qkv; head-split outputs.
// ---------------------------------------------------------------------------
__global__ __launch_bounds__(256)
void k_ln(const u16* __restrict__ qkvb,
          const float* __restrict__ gq, const float* __restrict__ bq,
          const float* __restrict__ gk, const float* __restrict__ bk,
          u16* __restrict__ qh, u16* __restrict__ kh) {
    __shared__ float red[8];
    const int tok = blockIdx.x;
    const int b = tok >> 11, s = tok & (S - 1);
    const int tid = threadIdx.x, lane = tid & 63, w = tid >> 6;

    #pragma unroll
    for (int part = 0; part < 2; ++part) {
        const int c0 = tid * 8;
        const u16* src = qkvb + (size_t)tok * E3 + part * D_MODEL + c0;
        u16 hx[8];
        *reinterpret_cast<uint4*>(hx) = *reinterpret_cast<const uint4*>(src);
        float x[8], sum = 0.f, sq = 0.f;
        #pragma unroll
        for (int j = 0; j < 8; ++j) { x[j] = bf2f(hx[j]); sum += x[j]; sq += x[j] * x[j]; }
        #pragma unroll
        for (int off = 1; off < 64; off <<= 1) {
            sum += __shfl_xor(sum, off, 64);
            sq  += __shfl_xor(sq,  off, 64);
        }
        __syncthreads();
        if (lane == 0) { red[w] = sum; red[4 + w] = sq; }
        __syncthreads();
        sum = red[0] + red[1] + red[2] + red[3];
        sq  = red[4] + red[5] + red[6] + red[7];
        const float mean = sum * (1.0f / D_MODEL);
        const float var  = fmaxf(sq * (1.0f / D_MODEL) - mean * mean, 0.0f);
        const float rstd = rsqrtf(var + LN_EPS);
        const float* g  = part ? gk : gq;
        const float* be = part ? bk : bq;
        u16 o[8];
        #pragma unroll
        for (int j = 0; j < 8; ++j)
            o[j] = f2bf((x[j] - mean) * rstd * g[c0 + j] + be[c0 + j]);
        const int h = c0 >> 7, d = c0 & (HEAD_DIM - 1);
        u16* dst = (part ? kh : qh) + ((size_t)((b * N_HEADS + h) * S + s)) * HEAD_DIM + d;
        *reinterpret_cast<uint4*>(dst) = *reinterpret_cast<uint4*>(o);
    }
}

// ---------------------------------------------------------------------------
// V transpose: qkv v-part [tok, 2048] bf16 -> vt [B, H, HEAD_DIM, S] bf16.
// ---------------------------------------------------------------------------
__global__ __launch_bounds__(256)
void k_vtrans(const u16* __restrict__ qkvb, u16* __restrict__ vt) {
    constexpr int LDT = 136;  // 128 + 8 pad
    __shared__ __align__(16) u16 tile[64 * LDT];
    const int blk = blockIdx.x;
    const int st = blk & 31, h = (blk >> 5) & 15, b = blk >> 9;
    const int s0 = st * 64;
    const int tid = threadIdx.x;

    #pragma unroll
    for (int i = 0; i < 4; ++i) {
        const int chunk = tid + i * 256;
        const int row = chunk >> 4, c8 = (chunk & 15) * 8;
        const u16* src = qkvb + (size_t)(b * S + s0 + row) * E3 + 2 * D_MODEL + h * HEAD_DIM + c8;
        *reinterpret_cast<uint4*>(&tile[row * LDT + c8]) = *reinterpret_cast<const uint4*>(src);
    }
    __syncthreads();
    #pragma unroll
    for (int i = 0; i < 4; ++i) {
        const int chunk = tid + i * 256;
        const int d = chunk >> 3, s8 = (chunk & 7) * 8;
        u16 o[8];
        #pragma unroll
        for (int j = 0; j < 8; ++j) o[j] = tile[(s8 + j) * LDT + d];
        u16* dst = vt + ((size_t)(b * N_HEADS + h) * HEAD_DIM + d) * S + s0 + s8;
        *reinterpret_cast<uint4*>(dst) = *reinterpret_cast<uint4*>(o);
    }
}

// ---------------------------------------------------------------------------
// Flash attention (causal + key bias), 128 q-rows per block, 64-key kv tiles.
// ---------------------------------------------------------------------------
__global__ __launch_bounds__(256)
void k_attn(const u16* __restrict__ qh, const u16* __restrict__ kh,
            const u16* __restrict__ vt, const float* __restrict__ bias,
            u16* __restrict__ ctx) {
    constexpr int BQ = 128, BKV = 64;
    constexpr int LDK = 136;
    constexpr int LDV = 72;
    constexpr int LDP = 72;
    __shared__ __align__(16) u16 Ks[64 * LDK];
    __shared__ __align__(16) u16 Vs[128 * LDV];
    __shared__ __align__(16) u16 Ps[128 * LDP];

    const int blk = blockIdx.x;
    const int bh = blk & 31;          // b*16 + h
    const int qi = 15 - (blk >> 5);   // heavy q-tiles dispatched first
    const int b = bh >> 4, h = bh & 15;
    const int q0 = qi * BQ;

    const int tid = threadIdx.x, lane = tid & 63, w = tid >> 6;
    const int quad = lane >> 4, l16 = lane & 15;

    const size_t bhS = (size_t)(b * N_HEADS + h) * S;
    const u16* Qt = qh + (bhS + q0) * HEAD_DIM;
    const u16* Kt = kh + bhS * HEAD_DIM;
    const u16* Vt = vt + (size_t)(b * N_HEADS + h) * HEAD_DIM * S;

    bf16x8 aq[2][4];
    #pragma unroll
    for (int mt = 0; mt < 2; ++mt)
        #pragma unroll
        for (int ks = 0; ks < 4; ++ks)
            aq[mt][ks] = *reinterpret_cast<const bf16x8*>(
                Qt + (size_t)(w * 32 + mt * 16 + l16) * HEAD_DIM + ks * 32 + quad * 8);

    f32x4 o[2][8] = {};
    float m_i[2][4], l_i[2][4];
    #pragma unroll
    for (int mt = 0; mt < 2; ++mt)
        #pragma unroll
        for (int r = 0; r < 4; ++r) { m_i[mt][r] = NEG_BIG; l_i[mt][r] = 0.f; }

    const float scale = 0.08838834764831845f;  // 1/sqrt(128)
    const int nkv = 2 * (qi + 1);

    for (int t = 0; t < nkv; ++t) {
        const int k0 = t * BKV;
        __syncthreads();
        #pragma unroll
        for (int i = 0; i < 4; ++i) {   // Ks: 64 keys x 128 d
            const int chunk = tid + i * 256;
            const int key = chunk >> 4, c8 = (chunk & 15) * 8;
            *reinterpret_cast<uint4*>(&Ks[key * LDK + c8]) =
                *reinterpret_cast<const uint4*>(Kt + (size_t)(k0 + key) * HEAD_DIM + c8);
        }
        #pragma unroll
        for (int i = 0; i < 4; ++i) {   // Vs: 128 d x 64 keys (V^T)
            const int chunk = tid + i * 256;
            const int d = chunk >> 3, s8 = (chunk & 7) * 8;
            *reinterpret_cast<uint4*>(&Vs[d * LDV + s8]) =
                *reinterpret_cast<const uint4*>(Vt + (size_t)d * S + k0 + s8);
        }
        __syncthreads();

        // QK^T
        f32x4 sc[2][4] = {};
        #pragma unroll
        for (int ks = 0; ks < 4; ++ks) {
            bf16x8 bk[4];
            #pragma unroll
            for (int nt = 0; nt < 4; ++nt)
                bk[nt] = *reinterpret_cast<const bf16x8*>(&Ks[(nt * 16 + l16) * LDK + ks * 32 + quad * 8]);
            #pragma unroll
            for (int mt = 0; mt < 2; ++mt)
                #pragma unroll
                for (int nt = 0; nt < 4; ++nt)
                    sc[mt][nt] = __builtin_amdgcn_mfma_f32_16x16x32_bf16(aq[mt][ks], bk[nt], sc[mt][nt], 0, 0, 0);
        }

        // scale + bias + causal mask (finite sentinel)
        float bv[4];
        #pragma unroll
        for (int nt = 0; nt < 4; ++nt) bv[nt] = bias[h * S + k0 + nt * 16 + l16];
        const bool need_mask = (t >= 2 * qi);
        #pragma unroll
        for (int mt = 0; mt < 2; ++mt)
            #pragma unroll
            for (int nt = 0; nt < 4; ++nt) {
                const int kpos = k0 + nt * 16 + l16;
                #pragma unroll
                for (int r = 0; r < 4; ++r) {
                    float v = sc[mt][nt][r] * scale + bv[nt];
                    if (need_mask) {
                        const int qpos = q0 + w * 32 + mt * 16 + quad * 4 + r;
                        if (kpos > qpos) v = NEG_BIG;
                    }
                    sc[mt][nt][r] = v;
                }
            }

        // online softmax (rows shared by the 16 lanes of a quad)
        #pragma unroll
        for (int mt = 0; mt < 2; ++mt)
            #pragma unroll
            for (int r = 0; r < 4; ++r) {
                float mx = fmaxf(fmaxf(sc[mt][0][r], sc[mt][1][r]), fmaxf(sc[mt][2][r], sc[mt][3][r]));
                mx = fmaxf(mx, __shfl_xor(mx, 1, 64));
                mx = fmaxf(mx, __shfl_xor(mx, 2, 64));
                mx = fmaxf(mx, __shfl_xor(mx, 4, 64));
                mx = fmaxf(mx, __shfl_xor(mx, 8, 64));
                const float mnew = fmaxf(m_i[mt][r], mx);
                const float alpha = __expf(m_i[mt][r] - mnew);
                float rs = 0.f;
                #pragma unroll
                for (int nt = 0; nt < 4; ++nt) {
                    const float p = __expf(sc[mt][nt][r] - mnew);
                    sc[mt][nt][r] = p;
                    rs += p;
                }
                rs += __shfl_xor(rs, 1, 64);
                rs += __shfl_xor(rs, 2, 64);
                rs += __shfl_xor(rs, 4, 64);
                rs += __shfl_xor(rs, 8, 64);
                l_i[mt][r] = l_i[mt][r] * alpha + rs;
                m_i[mt][r] = mnew;
                #pragma unroll
                for (int nt = 0; nt < 8; ++nt) o[mt][nt][r] *= alpha;
            }

        // P -> LDS (C-layout -> A-layout round trip)
        #pragma unroll
        for (int mt = 0; mt < 2; ++mt)
            #pragma unroll
            for (int nt = 0; nt < 4; ++nt)
                #pragma unroll
                for (int r = 0; r < 4; ++r)
                    Ps[(w * 32 + mt * 16 + quad * 4 + r) * LDP + nt * 16 + l16] = f2bf(sc[mt][nt][r]);

        __syncthreads();

        // PV: o += P @ V
        #pragma unroll
        for (int ks = 0; ks < 2; ++ks) {
            bf16x8 ap[2];
            #pragma unroll
            for (int mt = 0; mt < 2; ++mt)
                ap[mt] = *reinterpret_cast<const bf16x8*>(&Ps[(w * 32 + mt * 16 + l16) * LDP + ks * 32 + quad * 8]);
            #pragma unroll
            for (int nt = 0; nt < 8; ++nt) {
                const bf16x8 bvv = *reinterpret_cast<const bf16x8*>(&Vs[(nt * 16 + l16) * LDV + ks * 32 + quad * 8]);
                #pragma unroll
                for (int mt = 0; mt < 2; ++mt)
                    o[mt][nt] = __builtin_amdgcn_mfma_f32_16x16x32_bf16(ap[mt], bvv, o[mt][nt], 0, 0, 0);
            }
        }
    }

    // epilogue
    #pragma unroll
    for (int mt = 0; mt < 2; ++mt)
        #pragma unroll
        for (int r = 0; r < 4; ++r) {
            const float inv_l = 1.0f / fmaxf(l_i[mt][r], 1e-20f);
            const int row = q0 + w * 32 + mt * 16 + quad * 4 + r;
            u16* dst = ctx + (size_t)(b * S + row) * D_MODEL + h * HEAD_DIM;
            #pragma unroll
            for (int nt = 0; nt < 8; ++nt)
                dst[nt * 16 + l16] = f2bf(o[mt][nt][r] * inv_l);
        }
}

// ---------------------------------------------------------------------------
extern "C" void kernel_launch(void* const* d_in, const int* in_sizes, int n_in,
                              void* d_out, int out_size, void* d_ws, size_t ws_size,
                              hipStream_t stream) {
    const float* x        = (const float*)d_in[0];   // [B,S,D] fp32
    const float* attn_bias= (const float*)d_in[1];   // [1,H,1,S] fp32
    // d_in[2]: key_padding_mask — all True, no-op in reference
    const float* Wqkv_w   = (const float*)d_in[3];   // [3D, D] fp32
    const float* Wqkv_b   = (const float*)d_in[4];   // [3D] fp32
    const float* q_ln_g   = (const float*)d_in[5];
    const float* q_ln_b   = (const float*)d_in[6];
    const float* k_ln_g   = (const float*)d_in[7];
    const float* k_ln_b   = (const float*)d_in[8];
    const float* out_w    = (const float*)d_in[9];   // [D, D] fp32
    const float* out_b    = (const float*)d_in[10];

    char* ws = (char*)d_ws;
    u16* xb   = (u16*)ws; ws += (size_t)NTOK * D_MODEL * 2;   // 16.8 MB bf16 x; later reused for out_w bf16
    u16* qkvb = (u16*)ws; ws += (size_t)NTOK * E3 * 2;        // 50.3 MB
    u16* qhb  = (u16*)ws; ws += (size_t)NTOK * D_MODEL * 2;
    u16* khb  = (u16*)ws; ws += (size_t)NTOK * D_MODEL * 2;
    u16* vtb  = (u16*)ws; ws += (size_t)NTOK * D_MODEL * 2;   // total 117.4 MB
    u16* wqkvb = (u16*)d_out;  // 25.2 MB bf16 in d_out (33.5 MB); dead before GEMM2 writes d_out
    u16* ctxb  = qkvb;         // alias: qkv dead after ln+vtrans
    u16* outwb = xb;           // alias: x dead after GEMM1

    // 0) one-time fp32 -> bf16 conversions
    k_cvt<<<(NTOK * D_MODEL / 8 + 255) / 256, 256, 0, stream>>>(x, xb, NTOK * D_MODEL / 8);
    k_cvt<<<(E3 * D_MODEL / 8 + 255) / 256, 256, 0, stream>>>(Wqkv_w, wqkvb, E3 * D_MODEL / 8);
    // 1) QKV projection + bias + clip (bf16 in, bf16 out)
    k_gemm_bt<true, false><<<dim3(E3 / 128, NTOK / 128), 256, 0, stream>>>(
        xb, wqkvb, Wqkv_b, qkvb, NTOK, E3, D_MODEL);
    // 2) q/k LayerNorm + head split
    k_ln<<<NTOK, 256, 0, stream>>>(qkvb, q_ln_g, q_ln_b, k_ln_g, k_ln_b, qhb, khb);
    // 3) V transpose
    k_vtrans<<<BB * N_HEADS * (S / 64), 256, 0, stream>>>(qkvb, vtb);
    // 4) causal flash attention with key bias
    k_attn<<<BB * N_HEADS * (S / 128), 256, 0, stream>>>(qhb, khb, vtb, attn_bias, ctxb);
    // 4b) convert out_w (into xb space, dead now)
    k_cvt<<<(D_MODEL * D_MODEL / 8 + 255) / 256, 256, 0, stream>>>(out_w, outwb, D_MODEL * D_MODEL / 8);
    // 5) output projection (bf16 in, fp32 out)
    k_gemm_bt<false, true><<<dim3(D_MODEL / 128, NTOK / 128), 256, 0, stream>>>(
        ctxb, outwb, out_b, d_out, NTOK, D_MODEL, D_MODEL);
}